// Round 4
// baseline (133.826 us; speedup 1.0000x reference)
//
#include <hip/hip_runtime.h>
#include <hip/hip_bf16.h>

// Problem constants (fixed by reference)
#define BATCH 2
#define NPTS  8192
#define BN    (BATCH * NPTS)   // 16384
#define KNN   16
#define HEADS 4
#define HD    128              // HEADS*32
#define CIN   64
#define COUT  128
#define WCOLS 384              // [WqA1 | WkA1 | Wv] columns

using short8  = __attribute__((ext_vector_type(8))) short;
using float4v = __attribute__((ext_vector_type(4))) float;
using float2v = __attribute__((ext_vector_type(2))) float;

static __device__ __forceinline__ unsigned short f2bf(float x) {
    unsigned u = __float_as_uint(x);
    u += 0x7fffu + ((u >> 16) & 1u);          // round-to-nearest-even
    return (unsigned short)(u >> 16);
}
static __device__ __forceinline__ float bf_lo(unsigned u) { return __uint_as_float(u << 16); }
static __device__ __forceinline__ float bf_hi(unsigned u) { return __uint_as_float(u & 0xffff0000u); }
static __device__ __forceinline__ unsigned pack2(float a, float b) {
    return (unsigned)f2bf(a) | ((unsigned)f2bf(b) << 16);
}
// one packed uint (2 adjacent bf16 channels) -> float2v {even, odd}
static __device__ __forceinline__ float2v bf2pair(unsigned u) {
    float2v r;
    r.x = __uint_as_float(u << 16);
    r.y = __uint_as_float(u & 0xffff0000u);
    return r;
}

// ---- packed fp32 VOP3P (v_pk_*_f32): 2 f32 per instruction ----
static __device__ __forceinline__ float2v pk_add(float2v a, float2v b) {
    float2v d;
    asm("v_pk_add_f32 %0, %1, %2" : "=v"(d) : "v"(a), "v"(b));
    return d;
}
static __device__ __forceinline__ float2v pk_sub(float2v a, float2v b) {
    float2v d;
    asm("v_pk_add_f32 %0, %1, %2 neg_lo:[0,1] neg_hi:[0,1]" : "=v"(d) : "v"(a), "v"(b));
    return d;
}
static __device__ __forceinline__ float2v pk_mul(float2v a, float2v b) {
    float2v d;
    asm("v_pk_mul_f32 %0, %1, %2" : "=v"(d) : "v"(a), "v"(b));
    return d;
}
static __device__ __forceinline__ float2v pk_fma(float2v a, float2v b, float2v c) {
    float2v d;
    asm("v_pk_fma_f32 %0, %1, %2, %3" : "=v"(d) : "v"(a), "v"(b), "v"(c));
    return d;
}
static __device__ __forceinline__ float2v sx2(float2v v, int mask) {
    float2v r;
    r.x = __shfl_xor(v.x, mask, 64);
    r.y = __shfl_xor(v.y, mask, 64);
    return r;
}
static __device__ __forceinline__ unsigned cvt_pk_bf16(float lo, float hi) {
    unsigned r;
    asm("v_cvt_pk_bf16_f32 %0, %1, %2" : "=v"(r) : "v"(lo), "v"(hi));
    return r;
}

// ---------------------------------------------------------------------------
// Kernel P: fold weights into MFMA-ready transposed bf16 operands + xyz4 pack.
// ---------------------------------------------------------------------------
__global__ void prep_kernel(const float* __restrict__ Wk,
                            const float* __restrict__ Wv,
                            const float* __restrict__ Wq,
                            const float* __restrict__ A1,
                            const float* __restrict__ b1,
                            const float* __restrict__ P2,
                            const float* __restrict__ bp2,
                            const float* __restrict__ Wout,
                            const float* __restrict__ xyzs,
                            unsigned short* __restrict__ WcatT,
                            unsigned short* __restrict__ WoutT,
                            float* __restrict__ P2A1,
                            float* __restrict__ cvec,
                            float4* __restrict__ xyz4) {
    int t = blockIdx.x * blockDim.x + threadIdx.x;
    if (t < WCOLS * CIN) {                     // WcatT: u = n*64 + kk
        int n = t >> 6, kk = t & 63;
        float val;
        if (n < 2 * HD) {
            const float* w = (n < HD ? Wq : Wk) + kk * HD;
            int jj = n & (HD - 1);
            float acc = 0.f;
            #pragma unroll 4
            for (int m = 0; m < HD; m += 4) {
                float4 wr = *(const float4*)(w + m);
                acc += wr.x * A1[(m+0)*HD + jj] + wr.y * A1[(m+1)*HD + jj]
                     + wr.z * A1[(m+2)*HD + jj] + wr.w * A1[(m+3)*HD + jj];
            }
            val = acc;
        } else {
            val = Wv[kk * HD + (n - 2 * HD)];
        }
        WcatT[t] = f2bf(val);
    } else if (t < WCOLS * CIN + COUT * HD) {  // WoutT: u = n*128 + kk
        int u = t - WCOLS * CIN;
        int n = u >> 7, kk = u & 127;
        WoutT[u] = f2bf(Wout[kk * COUT + n]);
    } else if (t < WCOLS * CIN + COUT * HD + 3 * HD) {
        int u = t - (WCOLS * CIN + COUT * HD);
        int r = u / HD, j = u % HD;
        const float* w = P2 + r * HD;
        float acc = 0.f;
        #pragma unroll 4
        for (int m = 0; m < HD; m += 4) {
            float4 wr = *(const float4*)(w + m);
            acc += wr.x * A1[(m+0)*HD + j] + wr.y * A1[(m+1)*HD + j]
                 + wr.z * A1[(m+2)*HD + j] + wr.w * A1[(m+3)*HD + j];
        }
        P2A1[u] = acc;
    } else if (t < WCOLS * CIN + COUT * HD + 3 * HD + HD) {
        int j = t - (WCOLS * CIN + COUT * HD + 3 * HD);
        float acc = b1[j];
        #pragma unroll 4
        for (int m = 0; m < HD; m += 4) {
            float4 wr = *(const float4*)(bp2 + m);
            acc += wr.x * A1[(m+0)*HD + j] + wr.y * A1[(m+1)*HD + j]
                 + wr.z * A1[(m+2)*HD + j] + wr.w * A1[(m+3)*HD + j];
        }
        cvec[j] = acc;
    } else if (t < WCOLS * CIN + COUT * HD + 3 * HD + HD + BN) {
        int u = t - (WCOLS * CIN + COUT * HD + 3 * HD + HD);
        xyz4[u] = make_float4(xyzs[u*3], xyzs[u*3+1], xyzs[u*3+2], 0.f);
    }
}

// ---------------------------------------------------------------------------
// Kernel A (MFMA): QKVb[16384][384] bf16 = bf16(F) @ Wcat (+cvec on n<128).
// ---------------------------------------------------------------------------
#define AK 88
__global__ __launch_bounds__(256) void qkv_kernel(const float* __restrict__ F,
                                                  const unsigned short* __restrict__ WcatT,
                                                  const float* __restrict__ cvec,
                                                  unsigned short* __restrict__ QKVb) {
    __shared__ unsigned short Af[64 * AK];     // 11.3 KB
    __shared__ unsigned short Bf[WCOLS * AK];  // 67.6 KB
    int p0 = blockIdx.x * 64;
    int t = threadIdx.x;

    // stage A: 64x64 fp32 -> bf16
    #pragma unroll
    for (int i = 0; i < 4; ++i) {
        int v = t + i * 256;
        int row = v >> 4, c4 = (v & 15) * 4;
        float4 fa = *(const float4*)(F + (p0 + row) * CIN + c4);
        uint2 u = make_uint2(pack2(fa.x, fa.y), pack2(fa.z, fa.w));
        *(uint2*)(&Af[row * AK + c4]) = u;
    }
    // stage B: 384x64 bf16
    #pragma unroll
    for (int i = 0; i < 12; ++i) {
        int v = t + i * 256;                   // uint4 index: n = v>>3, j16 = v&7
        int n = v >> 3, j16 = v & 7;
        *(uint4*)(&Bf[n * AK + j16 * 8]) = ((const uint4*)WcatT)[v];
    }
    __syncthreads();

    int w = t >> 6, l = t & 63;
    int ml = l & 15, quad = l >> 4;
    int m0 = w * 16;

    short8 a0 = *(const short8*)(&Af[(m0 + ml) * AK + quad * 8]);
    short8 a1 = *(const short8*)(&Af[(m0 + ml) * AK + 32 + quad * 8]);

    #pragma unroll
    for (int nt = 0; nt < 24; ++nt) {
        short8 b0 = *(const short8*)(&Bf[(nt * 16 + ml) * AK + quad * 8]);
        short8 b1 = *(const short8*)(&Bf[(nt * 16 + ml) * AK + 32 + quad * 8]);
        float4v acc = {0.f, 0.f, 0.f, 0.f};
        acc = __builtin_amdgcn_mfma_f32_16x16x32_bf16(a0, b0, acc, 0, 0, 0);
        acc = __builtin_amdgcn_mfma_f32_16x16x32_bf16(a1, b1, acc, 0, 0, 0);
        int n = nt * 16 + ml;
        float cadd = (n < HD) ? cvec[n] : 0.f;
        #pragma unroll
        for (int r = 0; r < 4; ++r) {
            int row = p0 + m0 + quad * 4 + r;
            QKVb[row * WCOLS + n] = f2bf(acc[r] + cadd);
        }
    }
}

// ---------------------------------------------------------------------------
// Kernel B: wave-per-point attention, COALESCED gathers.
// lane: cs = lane&15 (channel-span: 8 ch = 16B), g = lane>>4 (nbr group).
// Load instr i fetches neighbor i*4+g's 16B at channel cs*8 -> each group's
// 16 lanes read one contiguous 256B row segment (4 lanes/64B-line).
// After the z/logit loop, lane holds logit partials for 4 nbrs x 4 heads;
// a 4-stage packed butterfly over the 16 cs-lanes lands the full logit of
// (nbr=(cs>>2)*4+g, head=cs&3); softmax + hb all-reduce over masks
// {4,8,16,32}; a/hb cross-mapped by bpermute; V accumulated per channel-span
// and g-reduced; write coalesced by g==0 lanes.
// ---------------------------------------------------------------------------
__global__ __launch_bounds__(256) void attn_kernel(
        const float4* __restrict__ xyz4, const int* __restrict__ kg,
        const unsigned short* __restrict__ QKVb,
        const float* __restrict__ P1, const float* __restrict__ bp1,
        const float* __restrict__ P2, const float* __restrict__ bp2,
        const float* __restrict__ P2A1,
        const float* __restrict__ A2, const float* __restrict__ b2,
        unsigned short* __restrict__ FUSEDb) {
    // channel-pair-major tables (pair pi = channels 2pi, 2pi+1)
    __shared__ float4 A2pA[64];   // {A2[2c][0],A2[2c+1][0],A2[2c][1],A2[2c+1][1]}
    __shared__ float4 A2pB[64];   // heads 2,3
    __shared__ float4 WApA[64];   // {P2A1[0][2c],P2A1[0][2c+1],P2A1[1][2c],P2A1[1][2c+1]}
    __shared__ float2 WApB[64];   // {P2A1[2][2c],P2A1[2][2c+1]}
    __shared__ float4 P2s[HD];    // (P2[0][ch], P2[1][ch], P2[2][ch], bp2[ch])
    int t = threadIdx.x;
    if (t < 64) {
        int c = t * 2;
        float4 a2l = *(const float4*)(A2 + c * 4);
        float4 a2h = *(const float4*)(A2 + (c + 1) * 4);
        A2pA[t] = make_float4(a2l.x, a2h.x, a2l.y, a2h.y);
        A2pB[t] = make_float4(a2l.z, a2h.z, a2l.w, a2h.w);
        WApA[t] = make_float4(P2A1[c], P2A1[c + 1], P2A1[HD + c], P2A1[HD + c + 1]);
        WApB[t] = make_float2(P2A1[2 * HD + c], P2A1[2 * HD + c + 1]);
    }
    if (t < HD) P2s[t] = make_float4(P2[t], P2[HD + t], P2[2 * HD + t], bp2[t]);
    __syncthreads();   // once per block; no further barriers

    int lane = t & 63;
    int p = blockIdx.x * 4 + (t >> 6);
    int b = p >> 13;                 // p / NPTS
    int cs = lane & 15, g = lane >> 4;

    // neighbor indices for this lane's 4 neighbors {i*4+g}
    int qn[4];
    #pragma unroll
    for (int i = 0; i < 4; ++i) qn[i] = b * NPTS + kg[p * KNN + i * 4 + g];

    // position MLP hidden for each neighbor
    float4 pw = xyz4[p];
    float h0v[4], h1v[4], h2v[4];
    #pragma unroll
    for (int i = 0; i < 4; ++i) {
        float4 qw = xyz4[qn[i]];
        float r0 = pw.x - qw.x, r1 = pw.y - qw.y, r2 = pw.z - qw.z;
        h0v[i] = fmaxf(r0*P1[0] + r1*P1[3] + r2*P1[6] + bp1[0], 0.f);
        h1v[i] = fmaxf(r0*P1[1] + r1*P1[4] + r2*P1[7] + bp1[1], 0.f);
        h2v[i] = fmaxf(r0*P1[2] + r1*P1[5] + r2*P1[8] + bp1[2], 0.f);
    }

    // coalesced loads: Q (broadcast), K rows (contiguous per group)
    uint4 qu = *(const uint4*)(QKVb + (size_t)p * WCOLS + cs * 8);
    uint4 ku[4];
    #pragma unroll
    for (int i = 0; i < 4; ++i)
        ku[i] = *(const uint4*)(QKVb + (size_t)qn[i] * WCOLS + HD + cs * 8);

    // h splats for packed math
    float2v hs0[4], hs1[4], hs2[4];
    #pragma unroll
    for (int i = 0; i < 4; ++i) {
        hs0[i] = (float2v){h0v[i], h0v[i]};
        hs1[i] = (float2v){h1v[i], h1v[i]};
        hs2[i] = (float2v){h2v[i], h2v[i]};
    }

    // z/logit loop: per channel pair (jp), per neighbor (i)
    float2v pl0[4], pl1[4], pl2[4], pl3[4];
    #pragma unroll
    for (int i = 0; i < 4; ++i) {
        pl0[i] = (float2v){0.f, 0.f}; pl1[i] = (float2v){0.f, 0.f};
        pl2[i] = (float2v){0.f, 0.f}; pl3[i] = (float2v){0.f, 0.f};
    }
    const unsigned* uq = (const unsigned*)&qu;
    #pragma unroll
    for (int jp = 0; jp < 4; ++jp) {
        int pi = cs * 4 + jp;
        float2v q2 = bf2pair(uq[jp]);
        float4 wa = WApA[pi];
        float2 wb = WApB[pi];
        float4 aA = A2pA[pi], aB = A2pB[pi];
        float2v wa01 = {wa.x, wa.y}, wa23 = {wa.z, wa.w}, wb01 = {wb.x, wb.y};
        float2v aA01 = {aA.x, aA.y}, aA23 = {aA.z, aA.w};
        float2v aB01 = {aB.x, aB.y}, aB23 = {aB.z, aB.w};
        #pragma unroll
        for (int i = 0; i < 4; ++i) {
            float2v k2 = bf2pair(((const unsigned*)&ku[i])[jp]);
            float2v acc = pk_sub(q2, k2);
            acc = pk_fma(hs0[i], wa01, acc);
            acc = pk_fma(hs1[i], wa23, acc);
            acc = pk_fma(hs2[i], wb01, acc);
            float2v z2;
            z2.x = fmaxf(acc.x, 0.f);
            z2.y = fmaxf(acc.y, 0.f);
            pl0[i] = pk_fma(z2, aA01, pl0[i]);
            pl1[i] = pk_fma(z2, aA23, pl1[i]);
            pl2[i] = pk_fma(z2, aB01, pl2[i]);
            pl3[i] = pk_fma(z2, aB23, pl3[i]);
        }
    }

    // issue V loads now (latency hidden under reduction/softmax)
    uint4 vu[4];
    #pragma unroll
    for (int i = 0; i < 4; ++i)
        vu[i] = *(const uint4*)(QKVb + (size_t)qn[i] * WCOLS + 2 * HD + cs * 8);

    // horizontal: lgt[i][h]; pack P[i]={h0,h1}, Qv[i]={h2,h3}
    float2v P[4], Qv[4];
    #pragma unroll
    for (int i = 0; i < 4; ++i) {
        P[i]  = (float2v){pl0[i].x + pl0[i].y, pl1[i].x + pl1[i].y};
        Qv[i] = (float2v){pl2[i].x + pl2[i].y, pl3[i].x + pl3[i].y};
    }

    // butterfly reduce-scatter over the 16 cs-lanes: lane cs ends with full
    // logit of val v = cs (bits [3:2]=i, [1:0]=h)
    bool hi8 = (cs & 8) != 0;
    float2v kA = hi8 ? P[2]  : P[0],  sA = hi8 ? P[0]  : P[2];
    float2v kB = hi8 ? Qv[2] : Qv[0], sB = hi8 ? Qv[0] : Qv[2];
    float2v kC = hi8 ? P[3]  : P[1],  sC = hi8 ? P[1]  : P[3];
    float2v kD = hi8 ? Qv[3] : Qv[1], sD = hi8 ? Qv[1] : Qv[3];
    kA = pk_add(kA, sx2(sA, 8));
    kB = pk_add(kB, sx2(sB, 8));
    kC = pk_add(kC, sx2(sC, 8));
    kD = pk_add(kD, sx2(sD, 8));
    bool hi4 = (cs & 4) != 0;
    float2v mP = hi4 ? kC : kA, sP = hi4 ? kA : kC;
    float2v mQ = hi4 ? kD : kB, sQ = hi4 ? kB : kD;
    mP = pk_add(mP, sx2(sP, 4));
    mQ = pk_add(mQ, sx2(sQ, 4));
    bool hi2 = (cs & 2) != 0;
    float2v mT = hi2 ? mQ : mP, sT = hi2 ? mP : mQ;
    mT = pk_add(mT, sx2(sT, 2));
    bool hi1 = (cs & 1) != 0;
    float Lm = hi1 ? mT.y : mT.x, Ls = hi1 ? mT.x : mT.y;
    float L = Lm + __shfl_xor(Ls, 1, 64);
    // L = logit(nbr = (cs>>2)*4 + g, head = cs&3); b2 cancels in softmax

    // softmax over the 16 neighbors (lane bits {2,3}=i, {4,5}=g)
    float mx = L;
    mx = fmaxf(mx, __shfl_xor(mx, 4, 64));
    mx = fmaxf(mx, __shfl_xor(mx, 8, 64));
    mx = fmaxf(mx, __shfl_xor(mx, 16, 64));
    mx = fmaxf(mx, __shfl_xor(mx, 32, 64));
    float e = __expf(L - mx);
    float ssum = e;
    ssum += __shfl_xor(ssum, 4, 64);
    ssum += __shfl_xor(ssum, 8, 64);
    ssum += __shfl_xor(ssum, 16, 64);
    ssum += __shfl_xor(ssum, 32, 64);
    float a = e / ssum;

    // hb = sum_nbr a[nbr][head] * h[nbr] for head = cs&3 (static h select)
    bool sb2 = (cs & 4) != 0, sb3 = (cs & 8) != 0;
    float h0s = sb3 ? (sb2 ? h0v[3] : h0v[2]) : (sb2 ? h0v[1] : h0v[0]);
    float h1s = sb3 ? (sb2 ? h1v[3] : h1v[2]) : (sb2 ? h1v[1] : h1v[0]);
    float h2s = sb3 ? (sb2 ? h2v[3] : h2v[2]) : (sb2 ? h2v[1] : h2v[0]);
    float ph0 = a * h0s, ph1 = a * h1s, ph2 = a * h2s;
    ph0 += __shfl_xor(ph0, 4, 64);  ph1 += __shfl_xor(ph1, 4, 64);  ph2 += __shfl_xor(ph2, 4, 64);
    ph0 += __shfl_xor(ph0, 8, 64);  ph1 += __shfl_xor(ph1, 8, 64);  ph2 += __shfl_xor(ph2, 8, 64);
    ph0 += __shfl_xor(ph0, 16, 64); ph1 += __shfl_xor(ph1, 16, 64); ph2 += __shfl_xor(ph2, 16, 64);
    ph0 += __shfl_xor(ph0, 32, 64); ph1 += __shfl_xor(ph1, 32, 64); ph2 += __shfl_xor(ph2, 32, 64);
    // value now uniform over bits {2,3,4,5}; depends only on head = cs&3

    // cross-map: this lane's V channels belong to head cs>>2
    float hq0 = __shfl(ph0, cs >> 2, 64);
    float hq1 = __shfl(ph1, cs >> 2, 64);
    float hq2 = __shfl(ph2, cs >> 2, 64);
    // attention weights for my 4 neighbors at my V-head
    int sbase = (lane & 48) | (cs >> 2);
    float av0 = __shfl(a, sbase | (0 << 2), 64);
    float av1 = __shfl(a, sbase | (1 << 2), 64);
    float av2 = __shfl(a, sbase | (2 << 2), 64);
    float av3 = __shfl(a, sbase | (3 << 2), 64);

    // V weighted accumulate over my 4 neighbors, then g-reduce
    float2v ap0 = {av0, av0}, ap1 = {av1, av1}, ap2 = {av2, av2}, ap3 = {av3, av3};
    float2v wv[4];
    #pragma unroll
    for (int jp = 0; jp < 4; ++jp) {
        float2v acc = pk_mul(ap0, bf2pair(((const unsigned*)&vu[0])[jp]));
        acc = pk_fma(ap1, bf2pair(((const unsigned*)&vu[1])[jp]), acc);
        acc = pk_fma(ap2, bf2pair(((const unsigned*)&vu[2])[jp]), acc);
        acc = pk_fma(ap3, bf2pair(((const unsigned*)&vu[3])[jp]), acc);
        wv[jp] = acc;
    }
    #pragma unroll
    for (int jp = 0; jp < 4; ++jp) {
        wv[jp] = pk_add(wv[jp], sx2(wv[jp], 16));
        wv[jp] = pk_add(wv[jp], sx2(wv[jp], 32));
    }

    // epilogue: fused = wv + hq @ P2 + bp2 ; write 16B/lane, g==0 lanes
    unsigned fw[4];
    #pragma unroll
    for (int jp = 0; jp < 4; ++jp) {
        int ch0 = cs * 8 + 2 * jp;
        float4 pA = P2s[ch0], pB = P2s[ch0 + 1];
        float flo = wv[jp].x + hq0 * pA.x + hq1 * pA.y + hq2 * pA.z + pA.w;
        float fhi = wv[jp].y + hq0 * pB.x + hq1 * pB.y + hq2 * pB.z + pB.w;
        fw[jp] = cvt_pk_bf16(flo, fhi);
    }
    if (g == 0) {
        uint4 fu = make_uint4(fw[0], fw[1], fw[2], fw[3]);
        *(uint4*)(FUSEDb + (size_t)p * HD + cs * 8) = fu;
    }
}

// ---------------------------------------------------------------------------
// Kernel C (MFMA): out[16384][128] = FUSEDb @ Wout + bout (fp32 out).
// ---------------------------------------------------------------------------
#define OK2 144
__global__ __launch_bounds__(256) void out_kernel(const unsigned short* __restrict__ FUSEDb,
                                                  const unsigned short* __restrict__ WoutT,
                                                  const float* __restrict__ bout,
                                                  float* __restrict__ out) {
    __shared__ unsigned short Af[64 * OK2];    // 18.4 KB
    __shared__ unsigned short Bf[HD * OK2];    // 36.9 KB
    int p0 = blockIdx.x * 64;
    int t = threadIdx.x;

    #pragma unroll
    for (int i = 0; i < 4; ++i) {              // stage A: 64 x 128 bf16
        int v = t + i * 256;
        int row = v >> 4, j16 = v & 15;
        *(uint4*)(&Af[row * OK2 + j16 * 8]) = ((const uint4*)FUSEDb)[(p0 + row) * 16 + j16];
    }
    #pragma unroll
    for (int i = 0; i < 8; ++i) {              // stage B: 128 x 128 bf16
        int v = t + i * 256;
        int n = v >> 4, j16 = v & 15;
        *(uint4*)(&Bf[n * OK2 + j16 * 8]) = ((const uint4*)WoutT)[v];
    }
    __syncthreads();

    int w = t >> 6, l = t & 63;
    int ml = l & 15, quad = l >> 4;
    int m0 = w * 16;

    short8 af[4];
    #pragma unroll
    for (int ks = 0; ks < 4; ++ks)
        af[ks] = *(const short8*)(&Af[(m0 + ml) * OK2 + ks * 32 + quad * 8]);

    #pragma unroll
    for (int nt = 0; nt < 8; ++nt) {
        float4v acc = {0.f, 0.f, 0.f, 0.f};
        #pragma unroll
        for (int ks = 0; ks < 4; ++ks) {
            short8 bf = *(const short8*)(&Bf[(nt * 16 + ml) * OK2 + ks * 32 + quad * 8]);
            acc = __builtin_amdgcn_mfma_f32_16x16x32_bf16(af[ks], bf, acc, 0, 0, 0);
        }
        int n = nt * 16 + ml;
        float bo = bout[n];
        #pragma unroll
        for (int r = 0; r < 4; ++r) {
            int row = p0 + m0 + quad * 4 + r;
            out[row * COUT + n] = acc[r] + bo;
        }
    }
}

// ---------------------------------------------------------------------------
extern "C" void kernel_launch(void* const* d_in, const int* in_sizes, int n_in,
                              void* d_out, int out_size, void* d_ws, size_t ws_size,
                              hipStream_t stream) {
    const float* xyzs = (const float*)d_in[0];
    const float* feat = (const float*)d_in[1];
    const int*   kg   = (const int*)  d_in[2];
    const float* Wk   = (const float*)d_in[3];
    const float* Wv   = (const float*)d_in[4];
    const float* Wq   = (const float*)d_in[5];
    const float* A1   = (const float*)d_in[6];
    const float* b1   = (const float*)d_in[7];
    const float* A2   = (const float*)d_in[8];
    const float* b2   = (const float*)d_in[9];
    const float* P1   = (const float*)d_in[10];
    const float* bp1  = (const float*)d_in[11];
    const float* P2   = (const float*)d_in[12];
    const float* bp2  = (const float*)d_in[13];
    const float* Wout = (const float*)d_in[14];
    const float* bout = (const float*)d_in[15];
    float* out = (float*)d_out;

    float* ws = (float*)d_ws;
    float* cvec = ws;                               // 128 fp32
    float* P2A1 = ws + 128;                         // 384 fp32  (total 512 fp32 = 2048 B)
    unsigned short* QKVb  = (unsigned short*)(ws + 512);         // BN*384 bf16 (12.6 MB)
    unsigned short* FUSEDb = QKVb + (size_t)BN * WCOLS;          // BN*128 bf16 (4 MB)
    unsigned short* WcatT = FUSEDb + (size_t)BN * HD;            // 384*64 bf16
    unsigned short* WoutT = WcatT + WCOLS * CIN;                 // 128*128 bf16
    float4* xyz4 = (float4*)(WoutT + COUT * HD);                 // BN float4 (256 KB)

    int prep_elems = WCOLS*CIN + COUT*HD + 3*HD + HD + BN;  // 57856
    prep_kernel<<<(prep_elems + 255) / 256, 256, 0, stream>>>(
        Wk, Wv, Wq, A1, b1, P2, bp2, Wout, xyzs, WcatT, WoutT, P2A1, cvec, xyz4);

    qkv_kernel<<<BN / 64, 256, 0, stream>>>(feat, WcatT, cvec, QKVb);

    attn_kernel<<<BN / 4, 256, 0, stream>>>(
        xyz4, kg, QKVb, P1, bp1, P2, bp2, P2A1, A2, b2, FUSEDb);

    out_kernel<<<BN / 64, 256, 0, stream>>>(FUSEDb, WoutT, bout, out);
}